// Round 2
// baseline (441.023 us; speedup 1.0000x reference)
//
#include <hip/hip_runtime.h>

#define P 10
#define PM 9
// lower-triangular flat index, requires a>=b
#define TRI(a,b) ((a)*((a)+1)/2 + (b))

__device__ __forceinline__ int tri_sym(int a, int b) { return a >= b ? TRI(a, b) : TRI(b, a); }

__global__ __launch_bounds__(256, 4)
void spodnet_kernel(const float* __restrict__ Theta,
                    const float* __restrict__ noise,
                    float* __restrict__ out,
                    int B, int K)
{
    int b = blockIdx.x * blockDim.x + threadIdx.x;
    if (b >= B) return;

    // ---- load Theta[b] lower triangle directly into Wl (float4 loads) ----
    float Wl[55];
    const float4* tp = reinterpret_cast<const float4*>(Theta + (size_t)b * (P * P));
#pragma unroll
    for (int q = 0; q < (P * P) / 4; q++) {
        float4 t = tp[q];
        float c4[4] = {t.x, t.y, t.z, t.w};
#pragma unroll
        for (int c = 0; c < 4; c++) {
            int e = 4 * q + c;
            int i = e / P, j = e % P;
            if (i >= j) Wl[TRI(i, j)] = c4[c];   // upper-tri lanes DCE'd
        }
    }

    // ---- Cholesky in place; diagonal stores 1/L[j][j] ----
#pragma unroll
    for (int j = 0; j < P; j++) {
        float s = Wl[TRI(j, j)];
#pragma unroll
        for (int k = 0; k < j; k++) s -= Wl[TRI(j, k)] * Wl[TRI(j, k)];
        float ilj = __builtin_amdgcn_rsqf(s);   // 1/sqrt(s), ~1ulp
        Wl[TRI(j, j)] = ilj;
#pragma unroll
        for (int i = j + 1; i < P; i++) {
            float s2 = Wl[TRI(i, j)];
#pragma unroll
            for (int k = 0; k < j; k++) s2 -= Wl[TRI(i, k)] * Wl[TRI(j, k)];
            Wl[TRI(i, j)] = s2 * ilj;
        }
    }

    // ---- L^-1 in place (diag already holds Li[j][j] = 1/L[j][j]) ----
#pragma unroll
    for (int i = 0; i < P; i++) {
#pragma unroll
        for (int j = i + 1; j < P; j++) {
            float s = Wl[TRI(j, i)] * Wl[TRI(i, i)];   // original L[j][i] * Li[i][i]
#pragma unroll
            for (int k = i + 1; k < j; k++) s += Wl[TRI(j, k)] * Wl[TRI(k, i)];
            Wl[TRI(j, i)] = -s * Wl[TRI(j, j)];        // * 1/L[j][j]
        }
    }

    // ---- lauum in place: W = Li^T * Li (lower triangle) ----
#pragma unroll
    for (int j = 0; j < P; j++) {
        float ajj = Wl[TRI(j, j)];
#pragma unroll
        for (int i = 0; i < j; i++) {
            float s = ajj * Wl[TRI(j, i)];
#pragma unroll
            for (int k = j + 1; k < P; k++) s += Wl[TRI(k, j)] * Wl[TRI(k, i)];
            Wl[TRI(j, i)] = s;
        }
        float sd = ajj * ajj;
#pragma unroll
        for (int k = j + 1; k < P; k++) sd += Wl[TRI(k, j)] * Wl[TRI(k, j)];
        Wl[TRI(j, j)] = sd;
    }

    // ---- K passes of 10 column updates ----
    float diag[P];
    const float gy = 1.0f;
    for (int k = 0; k < K; k++) {
#pragma unroll
        for (int col = 0; col < P; col++) {
            float v_[PM], w12[PM], y_[PM];
#pragma unroll
            for (int t = 0; t < PM; t++) v_[t] = noise[k * P * PM + col * PM + t]; // uniform -> s_load
            float w22 = Wl[TRI(col, col)];
#pragma unroll
            for (int t = 0; t < PM; t++) {
                int it = t < col ? t : t + 1;
                w12[t] = Wl[tri_sym(it, col)];
            }
            // y = W11 * v
#pragma unroll
            for (int t = 0; t < PM; t++) {
                int it = t < col ? t : t + 1;
                float s = 0.f;
#pragma unroll
                for (int u = 0; u < PM; u++) {
                    int iu = u < col ? u : u + 1;
                    s += Wl[tri_sym(it, iu)] * v_[u];
                }
                y_[t] = s;
            }
            float d = 0.f, schur = 0.f;
#pragma unroll
            for (int t = 0; t < PM; t++) { d += w12[t] * v_[t]; schur += v_[t] * y_[t]; }
            float t22n = gy + schur;
            diag[col] = t22n;
            // u = inv_T11*v = y - (d/w22)*w12 ; s1 = v^T u   (overwrite y_ with u)
            float dw = d * __builtin_amdgcn_rcpf(w22);
            float s1 = 0.f;
#pragma unroll
            for (int t = 0; t < PM; t++) { y_[t] = y_[t] - dw * w12[t]; s1 += v_[t] * y_[t]; }
            float w22n = __builtin_amdgcn_rcpf(t22n - s1);
            // w12n = -w22n * u   (overwrite y_ with w12n)
#pragma unroll
            for (int t = 0; t < PM; t++) y_[t] = -w22n * y_[t];
            // W11 <- W11 - (1/w22) w12 w12^T + w22n * w12n w12n^T   (lower triangle)
            float a = -__builtin_amdgcn_rcpf(w22);
#pragma unroll
            for (int t = 0; t < PM; t++) {
                int it = t < col ? t : t + 1;
                float pa = a * w12[t];
                float pb = w22n * y_[t];
#pragma unroll
                for (int u2 = 0; u2 <= t; u2++) {
                    int iu = u2 < col ? u2 : u2 + 1;
                    Wl[TRI(it, iu)] += pa * w12[u2] + pb * y_[u2];
                }
            }
#pragma unroll
            for (int t = 0; t < PM; t++) {
                int it = t < col ? t : t + 1;
                Wl[tri_sym(it, col)] = y_[t];
            }
            Wl[TRI(col, col)] = w22n;
        }
    }

    // ---- write output: off-diag = noise[K-1][max][min] (uniform), diag = t22n ----
    const float* nl = noise + (size_t)(K - 1) * P * PM;
    float4* op = reinterpret_cast<float4*>(out + (size_t)b * (P * P));
#pragma unroll
    for (int q = 0; q < (P * P) / 4; q++) {
        float ov[4];
#pragma unroll
        for (int c = 0; c < 4; c++) {
            int e = 4 * q + c; int i = e / P, j = e % P;
            ov[c] = (i == j) ? diag[i] : nl[(i > j ? i : j) * PM + (i < j ? i : j)];
        }
        float4 o; o.x = ov[0]; o.y = ov[1]; o.z = ov[2]; o.w = ov[3];
        op[q] = o;
    }
}

extern "C" void kernel_launch(void* const* d_in, const int* in_sizes, int n_in,
                              void* d_out, int out_size, void* d_ws, size_t ws_size,
                              hipStream_t stream) {
    const float* Theta = (const float*)d_in[0];
    const float* noise = (const float*)d_in[1];
    float* out = (float*)d_out;
    int B = in_sizes[0] / (P * P);
    int K = in_sizes[1] / (P * PM);
    int threads = 256;
    int blocks = (B + threads - 1) / threads;
    hipLaunchKernelGGL(spodnet_kernel, dim3(blocks), dim3(threads), 0, stream,
                       Theta, noise, out, B, K);
}

// Round 4
// 428.756 us; speedup vs baseline: 1.0286x; 1.0286x over previous
//
#include <hip/hip_runtime.h>

#define P 10
#define PM 9
// lower-triangular flat index, requires a>=b
#define TRI(a,b) ((a)*((a)+1)/2 + (b))

typedef float vfloat4 __attribute__((ext_vector_type(4)));   // clang vector: ok for nontemporal builtin

__device__ __forceinline__ int tri_sym(int a, int b) { return a >= b ? TRI(a, b) : TRI(b, a); }

// One sweep of P column updates. FINAL=true: W state is dead after col P-1's
// t22n, so skip the last column's W update entirely (~150 VALU ops).
template<bool FINAL>
__device__ __forceinline__ void sweep(float* __restrict__ Wl, float* __restrict__ diag,
                                      const float* __restrict__ nv)
{
#pragma unroll
    for (int col = 0; col < P; col++) {
        float v_[PM], w12[PM], y_[PM];
#pragma unroll
        for (int t = 0; t < PM; t++) v_[t] = nv[col * PM + t];   // wave-uniform -> s_load
        float w22 = Wl[TRI(col, col)];
#pragma unroll
        for (int t = 0; t < PM; t++) {
            int it = t < col ? t : t + 1;
            w12[t] = Wl[tri_sym(it, col)];
        }
        // y = W11 * v
#pragma unroll
        for (int t = 0; t < PM; t++) {
            int it = t < col ? t : t + 1;
            float s = 0.f;
#pragma unroll
            for (int u = 0; u < PM; u++) {
                int iu = u < col ? u : u + 1;
                s += Wl[tri_sym(it, iu)] * v_[u];
            }
            y_[t] = s;
        }
        float d = 0.f, schur = 0.f;
#pragma unroll
        for (int t = 0; t < PM; t++) { d += w12[t] * v_[t]; schur += v_[t] * y_[t]; }
        float t22n = 1.0f + schur;
        diag[col] = t22n;
        if (FINAL && col == P - 1) return;   // everything below only feeds dead W
        // u = inv_T11*v = y - (d/w22)*w12 ; s1 = v^T u   (overwrite y_ with u)
        float dw = d * __builtin_amdgcn_rcpf(w22);
        float s1 = 0.f;
#pragma unroll
        for (int t = 0; t < PM; t++) { y_[t] = y_[t] - dw * w12[t]; s1 += v_[t] * y_[t]; }
        float w22n = __builtin_amdgcn_rcpf(t22n - s1);
        // w12n = -w22n * u   (overwrite y_ with w12n)
#pragma unroll
        for (int t = 0; t < PM; t++) y_[t] = -w22n * y_[t];
        // W11 <- W11 - (1/w22) w12 w12^T + w22n * w12n w12n^T   (lower triangle)
        float a = -__builtin_amdgcn_rcpf(w22);
#pragma unroll
        for (int t = 0; t < PM; t++) {
            int it = t < col ? t : t + 1;
            float pa = a * w12[t];
            float pb = w22n * y_[t];
#pragma unroll
            for (int u2 = 0; u2 <= t; u2++) {
                int iu = u2 < col ? u2 : u2 + 1;
                Wl[TRI(it, iu)] += pa * w12[u2] + pb * y_[u2];
            }
        }
#pragma unroll
        for (int t = 0; t < PM; t++) {
            int it = t < col ? t : t + 1;
            Wl[tri_sym(it, col)] = y_[t];
        }
        Wl[TRI(col, col)] = w22n;
    }
}

__global__ __launch_bounds__(256, 2)   // cap 256 regs: >> ~160 live floats, no scratch
void spodnet_kernel(const float* __restrict__ Theta,
                    const float* __restrict__ noise,
                    float* __restrict__ out,
                    int B, int K)
{
    int b = blockIdx.x * blockDim.x + threadIdx.x;
    if (b >= B) return;

    // ---- load Theta[b] lower triangle directly into Wl (float4 loads) ----
    float Wl[55];
    const float4* tp = reinterpret_cast<const float4*>(Theta + (size_t)b * (P * P));
#pragma unroll
    for (int q = 0; q < (P * P) / 4; q++) {
        float4 t = tp[q];
        float c4[4] = {t.x, t.y, t.z, t.w};
#pragma unroll
        for (int c = 0; c < 4; c++) {
            int e = 4 * q + c;
            int i = e / P, j = e % P;
            if (i >= j) Wl[TRI(i, j)] = c4[c];   // upper-tri lanes DCE'd
        }
    }

    // ---- Cholesky in place; diagonal stores 1/L[j][j] ----
#pragma unroll
    for (int j = 0; j < P; j++) {
        float s = Wl[TRI(j, j)];
#pragma unroll
        for (int k = 0; k < j; k++) s -= Wl[TRI(j, k)] * Wl[TRI(j, k)];
        float ilj = __builtin_amdgcn_rsqf(s);
        Wl[TRI(j, j)] = ilj;
#pragma unroll
        for (int i = j + 1; i < P; i++) {
            float s2 = Wl[TRI(i, j)];
#pragma unroll
            for (int k = 0; k < j; k++) s2 -= Wl[TRI(i, k)] * Wl[TRI(j, k)];
            Wl[TRI(i, j)] = s2 * ilj;
        }
    }

    // ---- L^-1 in place (diag already holds Li[j][j] = 1/L[j][j]) ----
#pragma unroll
    for (int i = 0; i < P; i++) {
#pragma unroll
        for (int j = i + 1; j < P; j++) {
            float s = Wl[TRI(j, i)] * Wl[TRI(i, i)];   // original L[j][i] * Li[i][i]
#pragma unroll
            for (int k = i + 1; k < j; k++) s += Wl[TRI(j, k)] * Wl[TRI(k, i)];
            Wl[TRI(j, i)] = -s * Wl[TRI(j, j)];        // * 1/L[j][j]
        }
    }

    // ---- lauum in place: W = Li^T * Li (lower triangle) ----
#pragma unroll
    for (int j = 0; j < P; j++) {
        float ajj = Wl[TRI(j, j)];
#pragma unroll
        for (int i = 0; i < j; i++) {
            float s = ajj * Wl[TRI(j, i)];
#pragma unroll
            for (int k = j + 1; k < P; k++) s += Wl[TRI(k, j)] * Wl[TRI(k, i)];
            Wl[TRI(j, i)] = s;
        }
        float sd = ajj * ajj;
#pragma unroll
        for (int k = j + 1; k < P; k++) sd += Wl[TRI(k, j)] * Wl[TRI(k, j)];
        Wl[TRI(j, j)] = sd;
    }

    // ---- K-1 full passes + one final (tail-trimmed) pass ----
    float diag[P];
    for (int k = 0; k < K - 1; k++)
        sweep<false>(Wl, diag, noise + (size_t)k * P * PM);
    sweep<true>(Wl, diag, noise + (size_t)(K - 1) * P * PM);

    // ---- write output: off-diag = noise[K-1][max][min] (uniform), diag = t22n ----
    const float* nl = noise + (size_t)(K - 1) * P * PM;
    vfloat4* op = reinterpret_cast<vfloat4*>(out + (size_t)b * (P * P));
#pragma unroll
    for (int q = 0; q < (P * P) / 4; q++) {
        float ov[4];
#pragma unroll
        for (int c = 0; c < 4; c++) {
            int e = 4 * q + c; int i = e / P, j = e % P;
            ov[c] = (i == j) ? diag[i] : nl[(i > j ? i : j) * PM + (i < j ? i : j)];
        }
        vfloat4 o = {ov[0], ov[1], ov[2], ov[3]};
        __builtin_nontemporal_store(o, op + q);   // never re-read; keep L3 for input
    }
}

extern "C" void kernel_launch(void* const* d_in, const int* in_sizes, int n_in,
                              void* d_out, int out_size, void* d_ws, size_t ws_size,
                              hipStream_t stream) {
    const float* Theta = (const float*)d_in[0];
    const float* noise = (const float*)d_in[1];
    float* out = (float*)d_out;
    int B = in_sizes[0] / (P * P);
    int K = in_sizes[1] / (P * PM);
    int threads = 256;
    int blocks = (B + threads - 1) / threads;
    hipLaunchKernelGGL(spodnet_kernel, dim3(blocks), dim3(threads), 0, stream,
                       Theta, noise, out, B, K);
}